// Round 1
// baseline (305.027 us; speedup 1.0000x reference)
//
#include <hip/hip_runtime.h>
#include <hip/hip_bf16.h>

#define B_   2
#define S_   2048
#define E_   1024
#define H_   16
#define HD_  64
#define E3_  3072
#define M_   4096   // B*S

using short8 = __attribute__((ext_vector_type(8))) short;
using f32x4  = __attribute__((ext_vector_type(4))) float;

__device__ __forceinline__ float bf2f(unsigned short u) {
  union { unsigned v; float f; } t; t.v = ((unsigned)u) << 16; return t.f;
}
__device__ __forceinline__ unsigned short f2bf(float f) {
  union { float f; unsigned v; } t; t.f = f;
  unsigned r = t.v + 0x7FFFu + ((t.v >> 16) & 1u);  // RNE
  return (unsigned short)(r >> 16);
}

__device__ __forceinline__ void gload16(const void* g, void* l) {
  __builtin_amdgcn_global_load_lds(
      (const __attribute__((address_space(1))) unsigned int*)g,
      (__attribute__((address_space(3))) unsigned int*)l, 16, 0, 0);
}

// ---------------- f32 -> bf16 convert ----------------
__global__ void cvt_f32_bf16(const float* __restrict__ in,
                             unsigned short* __restrict__ out, int n) {
  int i = (blockIdx.x * blockDim.x + threadIdx.x) * 4;
  if (i < n) {
    float4 v = *(const float4*)(in + i);
    ushort4 o;
    o.x = f2bf(v.x); o.y = f2bf(v.y); o.z = f2bf(v.z); o.w = f2bf(v.w);
    *(ushort4*)(out + i) = o;
  }
}

// ---------------- W [K][N] f32 -> WT [N][K] bf16 ----------------
__global__ void transpose_bf16(const float* __restrict__ W,
                               unsigned short* __restrict__ WT, int K, int N) {
  __shared__ float tile[32][33];
  int bn = blockIdx.x * 32, bk = blockIdx.y * 32;
  int tx = threadIdx.x & 31, ty = threadIdx.x >> 5;  // 32 x 8
  #pragma unroll
  for (int i = 0; i < 32; i += 8)
    tile[ty + i][tx] = W[(size_t)(bk + ty + i) * N + bn + tx];
  __syncthreads();
  #pragma unroll
  for (int i = 0; i < 32; i += 8)
    WT[(size_t)(bn + ty + i) * K + bk + tx] = f2bf(tile[tx][ty + i]);
}

// ---------------- 128x128 bf16 MFMA GEMM, B^T layout, fused bias ----------------
// A [M][K] bf16, BT [N][K] bf16, bias [N] f32, C [M][N] (bf16 or f32)
template <bool OUT_BF16>
__global__ __launch_bounds__(256) void gemm_bt_bias(
    const unsigned short* __restrict__ A,
    const unsigned short* __restrict__ BT,
    const float* __restrict__ bias,
    void* __restrict__ Cp, int M, int N, int K) {
  __shared__ __align__(16) unsigned short As[128 * 32];
  __shared__ __align__(16) unsigned short Bs[128 * 32];
  const int t = threadIdx.x;
  const int lane = t & 63, w = t >> 6;
  const int wr = w >> 1, wc = w & 1;
  const int m0 = blockIdx.y * 128, n0 = blockIdx.x * 128;
  const int lrow = lane & 15, lk = (lane >> 4) * 8;
  const int ar = t >> 2, ac = (t & 3) * 8;  // staging row/col

  f32x4 acc[4][4];
  const f32x4 z = {0.f, 0.f, 0.f, 0.f};
  #pragma unroll
  for (int i = 0; i < 4; ++i)
    #pragma unroll
    for (int j = 0; j < 4; ++j) acc[i][j] = z;

  for (int k0 = 0; k0 < K; k0 += 32) {
    __syncthreads();  // all waves done reading previous tile
    #pragma unroll
    for (int i = 0; i < 2; ++i) {
      gload16(A  + (size_t)(m0 + i * 64 + ar) * K + k0 + ac,
              &As[(i * 64 + ar) * 32 + ac]);
      gload16(BT + (size_t)(n0 + i * 64 + ar) * K + k0 + ac,
              &Bs[(i * 64 + ar) * 32 + ac]);
    }
    __syncthreads();  // drains vmcnt -> tiles ready

    short8 af[4], bf[4];
    #pragma unroll
    for (int m = 0; m < 4; ++m)
      af[m] = *(const short8*)&As[(wr * 64 + m * 16 + lrow) * 32 + lk];
    #pragma unroll
    for (int n = 0; n < 4; ++n)
      bf[n] = *(const short8*)&Bs[(wc * 64 + n * 16 + lrow) * 32 + lk];
    #pragma unroll
    for (int m = 0; m < 4; ++m)
      #pragma unroll
      for (int n = 0; n < 4; ++n)
        acc[m][n] = __builtin_amdgcn_mfma_f32_16x16x32_bf16(af[m], bf[n],
                                                            acc[m][n], 0, 0, 0);
  }

  const int r0 = (lane >> 4) * 4, c0 = lane & 15;
  #pragma unroll
  for (int m = 0; m < 4; ++m) {
    #pragma unroll
    for (int n = 0; n < 4; ++n) {
      int row = m0 + wr * 64 + m * 16 + r0;
      int col = n0 + wc * 64 + n * 16 + c0;
      float bv = bias[col];
      #pragma unroll
      for (int r = 0; r < 4; ++r) {
        float v = acc[m][n][r] + bv;
        if (OUT_BF16)
          ((unsigned short*)Cp)[(size_t)(row + r) * N + col] = f2bf(v);
        else
          ((float*)Cp)[(size_t)(row + r) * N + col] = v;
      }
    }
  }
}

// ---------------- flash attention (causal), 64 q-rows/block ----------------
// qkv [B][S][3E] bf16 (q at col 0, k at E_, v at 2E_), out [B][S][E] bf16
__global__ __launch_bounds__(256) void flash_attn(
    const unsigned short* __restrict__ qkv,
    unsigned short* __restrict__ aout) {
  __shared__ __align__(16) unsigned short Ks[32 * 64];      // [krow][d]
  __shared__ __align__(16) unsigned short Vs[64 * 32];      // [d][krow]
  __shared__ __align__(16) unsigned short Ps[4][16 * 32];   // per-wave P

  const int t = threadIdx.x, lane = t & 63, w = t >> 6;
  const int qt = blockIdx.x, bh = blockIdx.y;
  const int b = bh >> 4, h = bh & 15;
  const int lrow = lane & 15, lk = (lane >> 4) * 8;
  const size_t basebs = (size_t)b * S_;

  // Q fragments, resident in registers for the whole block
  short8 qf[2];
  {
    const int qrow = qt * 64 + w * 16 + lrow;
    const unsigned short* qp = qkv + (basebs + qrow) * E3_ + h * HD_;
    qf[0] = *(const short8*)(qp + lk);
    qf[1] = *(const short8*)(qp + 32 + lk);
  }

  float m_r[4], l_r[4];
  f32x4 o_acc[4];
  const f32x4 z = {0.f, 0.f, 0.f, 0.f};
  #pragma unroll
  for (int r = 0; r < 4; ++r) { m_r[r] = -1e30f; l_r[r] = 0.f; }
  #pragma unroll
  for (int n = 0; n < 4; ++n) o_acc[n] = z;

  const int nkt = 2 * qt + 2;           // k-tiles of 32 covering k <= q_max
  const int kr = t >> 3, kc = (t & 7) * 8;
  const int qrow_lane = qt * 64 + w * 16 + (lane >> 4) * 4;  // + r

  for (int kt = 0; kt < nkt; ++kt) {
    const int k0 = kt * 32;
    __syncthreads();  // previous tile fully consumed
    // stage K tile [32][64] (lane-linear -> async DMA)
    gload16(qkv + (basebs + k0 + kr) * E3_ + E_ + h * HD_ + kc, &Ks[t * 8]);
    // stage V transposed: Vs[d][k]
    {
      short8 v = *(const short8*)(qkv + (basebs + k0 + kr) * E3_ + 2 * E_ +
                                  h * HD_ + kc);
      #pragma unroll
      for (int j = 0; j < 8; ++j) Vs[(kc + j) * 32 + kr] = (unsigned short)v[j];
    }
    __syncthreads();  // vmcnt+lgkm drained

    // QK^T: S[16][32] per wave, two 16-col fragments
    f32x4 sc[2];
    #pragma unroll
    for (int n = 0; n < 2; ++n) {
      short8 kf0 = *(const short8*)&Ks[(n * 16 + lrow) * 64 + lk];
      short8 kf1 = *(const short8*)&Ks[(n * 16 + lrow) * 64 + 32 + lk];
      sc[n] = __builtin_amdgcn_mfma_f32_16x16x32_bf16(qf[0], kf0, z, 0, 0, 0);
      sc[n] = __builtin_amdgcn_mfma_f32_16x16x32_bf16(qf[1], kf1, sc[n], 0, 0, 0);
    }

    // online softmax (rows live in 16-lane groups; reduce via shfl_xor)
    #pragma unroll
    for (int r = 0; r < 4; ++r) {
      float s0 = sc[0][r] * 0.125f;
      float s1 = sc[1][r] * 0.125f;
      const int qg = qrow_lane + r;
      if (k0 + (lane & 15) > qg)      s0 = -1e30f;
      if (k0 + 16 + (lane & 15) > qg) s1 = -1e30f;
      float tm = fmaxf(s0, s1);
      #pragma unroll
      for (int off = 1; off < 16; off <<= 1)
        tm = fmaxf(tm, __shfl_xor(tm, off));
      float mnew = fmaxf(m_r[r], tm);
      float alpha = __expf(m_r[r] - mnew);
      float p0 = __expf(s0 - mnew);
      float p1 = __expf(s1 - mnew);
      m_r[r] = mnew;
      float ts = p0 + p1;
      #pragma unroll
      for (int off = 1; off < 16; off <<= 1)
        ts += __shfl_xor(ts, off);
      l_r[r] = l_r[r] * alpha + ts;
      #pragma unroll
      for (int n = 0; n < 4; ++n) o_acc[n][r] *= alpha;
      const int prow = (lane >> 4) * 4 + r;
      Ps[w][prow * 32 + (lane & 15)]      = f2bf(p0);
      Ps[w][prow * 32 + 16 + (lane & 15)] = f2bf(p1);
    }

    // PV: O[16][64] += P[16][32] * V[32][64]
    short8 pa = *(const short8*)&Ps[w][lrow * 32 + lk];
    #pragma unroll
    for (int n = 0; n < 4; ++n) {
      short8 vb = *(const short8*)&Vs[(n * 16 + lrow) * 32 + lk];
      o_acc[n] = __builtin_amdgcn_mfma_f32_16x16x32_bf16(pa, vb, o_acc[n], 0, 0, 0);
    }
  }

  // epilogue: normalize and store merged-head layout
  #pragma unroll
  for (int n = 0; n < 4; ++n) {
    #pragma unroll
    for (int r = 0; r < 4; ++r) {
      int row = qrow_lane + r;
      aout[(basebs + row) * E_ + h * HD_ + n * 16 + (lane & 15)] =
          f2bf(o_acc[n][r] / l_r[r]);
    }
  }
}

extern "C" void kernel_launch(void* const* d_in, const int* in_sizes, int n_in,
                              void* d_out, int out_size, void* d_ws, size_t ws_size,
                              hipStream_t stream) {
  const float* X  = (const float*)d_in[0];
  const float* Wa = (const float*)d_in[1];
  const float* ba = (const float*)d_in[2];
  const float* Wp = (const float*)d_in[3];
  const float* bp = (const float*)d_in[4];
  float* out = (float*)d_out;

  char* ws = (char*)d_ws;
  unsigned short* Xb  = (unsigned short*)ws; ws += (size_t)M_ * E_ * 2;
  unsigned short* WaT = (unsigned short*)ws; ws += (size_t)E3_ * E_ * 2;
  unsigned short* WpT = (unsigned short*)ws; ws += (size_t)E_ * E_ * 2;
  unsigned short* QKV = (unsigned short*)ws; ws += (size_t)M_ * E3_ * 2;
  unsigned short* AO  = (unsigned short*)ws; ws += (size_t)M_ * E_ * 2;
  // total: 48 MB

  cvt_f32_bf16<<<(M_ * E_ / 4 + 255) / 256, 256, 0, stream>>>(X, Xb, M_ * E_);
  transpose_bf16<<<dim3(E3_ / 32, E_ / 32), 256, 0, stream>>>(Wa, WaT, E_, E3_);
  transpose_bf16<<<dim3(E_ / 32, E_ / 32), 256, 0, stream>>>(Wp, WpT, E_, E_);
  gemm_bt_bias<true><<<dim3(E3_ / 128, M_ / 128), 256, 0, stream>>>(
      Xb, WaT, ba, QKV, M_, E3_, E_);
  flash_attn<<<dim3(S_ / 64, B_ * H_), 256, 0, stream>>>(QKV, AO);
  gemm_bt_bias<false><<<dim3(E_ / 128, M_ / 128), 256, 0, stream>>>(
      AO, WpT, bp, out, M_, E_, E_);
}

// Round 2
// 213.272 us; speedup vs baseline: 1.4302x; 1.4302x over previous
//
#include <hip/hip_runtime.h>
#include <hip/hip_bf16.h>

#define B_   2
#define S_   2048
#define E_   1024
#define H_   16
#define HD_  64
#define E3_  3072
#define M_   4096   // B*S
#define QKS  2048   // stride of QK buffer

using short8 = __attribute__((ext_vector_type(8))) short;
using f32x4  = __attribute__((ext_vector_type(4))) float;

__device__ __forceinline__ unsigned short f2bf(float f) {
  union { float f; unsigned v; } t; t.f = f;
  unsigned r = t.v + 0x7FFFu + ((t.v >> 16) & 1u);  // RNE
  return (unsigned short)(r >> 16);
}

__device__ __forceinline__ void gload16(const void* g, void* l) {
  __builtin_amdgcn_global_load_lds(
      (const __attribute__((address_space(1))) unsigned int*)g,
      (__attribute__((address_space(3))) unsigned int*)l, 16, 0, 0);
}

// ---------------- f32 -> bf16 convert ----------------
__global__ void cvt_f32_bf16(const float* __restrict__ in,
                             unsigned short* __restrict__ out, int n) {
  int i = (blockIdx.x * blockDim.x + threadIdx.x) * 4;
  if (i < n) {
    float4 v = *(const float4*)(in + i);
    ushort4 o;
    o.x = f2bf(v.x); o.y = f2bf(v.y); o.z = f2bf(v.z); o.w = f2bf(v.w);
    *(ushort4*)(out + i) = o;
  }
}

// ---------------- W [K][N] f32 -> WT [N][K] bf16 ----------------
__global__ void transpose_bf16(const float* __restrict__ W,
                               unsigned short* __restrict__ WT, int K, int N) {
  __shared__ float tile[32][33];
  int bn = blockIdx.x * 32, bk = blockIdx.y * 32;
  int tx = threadIdx.x & 31, ty = threadIdx.x >> 5;  // 32 x 8
  #pragma unroll
  for (int i = 0; i < 32; i += 8)
    tile[ty + i][tx] = W[(size_t)(bk + ty + i) * N + bn + tx];
  __syncthreads();
  #pragma unroll
  for (int i = 0; i < 32; i += 8)
    WT[(size_t)(bn + ty + i) * K + bk + tx] = f2bf(tile[tx][ty + i]);
}

// ---------------- 128x128 bf16 MFMA GEMM, B^T layout, fused bias ----------------
// MODE 0: f32 out, ldc = N.
// MODE 1: qkv split -> cols < 2048 as bf16 into Cbf (ldc 2048),
//         cols >= 2048 (the V block) transposed into Vt[bh][d][s].
template <int MODE>
__global__ __launch_bounds__(256) void gemm_bt_bias(
    const unsigned short* __restrict__ A,
    const unsigned short* __restrict__ BT,
    const float* __restrict__ bias,
    float* __restrict__ Cf,
    unsigned short* __restrict__ Cbf,
    unsigned short* __restrict__ Vt,
    int M, int N, int K) {
  __shared__ __align__(16) unsigned short As[128 * 32];
  __shared__ __align__(16) unsigned short Bs[128 * 32];
  const int t = threadIdx.x;
  const int lane = t & 63, w = t >> 6;
  const int wr = w >> 1, wc = w & 1;
  const int m0 = blockIdx.y * 128, n0 = blockIdx.x * 128;
  const int lrow = lane & 15, lk = (lane >> 4) * 8;
  const int ar = t >> 2, ac = (t & 3) * 8;  // staging row/col

  f32x4 acc[4][4];
  const f32x4 z = {0.f, 0.f, 0.f, 0.f};
  #pragma unroll
  for (int i = 0; i < 4; ++i)
    #pragma unroll
    for (int j = 0; j < 4; ++j) acc[i][j] = z;

  for (int k0 = 0; k0 < K; k0 += 32) {
    __syncthreads();
    #pragma unroll
    for (int i = 0; i < 2; ++i) {
      gload16(A  + (size_t)(m0 + i * 64 + ar) * K + k0 + ac,
              &As[(i * 64 + ar) * 32 + ac]);
      gload16(BT + (size_t)(n0 + i * 64 + ar) * K + k0 + ac,
              &Bs[(i * 64 + ar) * 32 + ac]);
    }
    __syncthreads();

    short8 af[4], bf[4];
    #pragma unroll
    for (int m = 0; m < 4; ++m)
      af[m] = *(const short8*)&As[(wr * 64 + m * 16 + lrow) * 32 + lk];
    #pragma unroll
    for (int n = 0; n < 4; ++n)
      bf[n] = *(const short8*)&Bs[(wc * 64 + n * 16 + lrow) * 32 + lk];
    #pragma unroll
    for (int m = 0; m < 4; ++m)
      #pragma unroll
      for (int n = 0; n < 4; ++n)
        acc[m][n] = __builtin_amdgcn_mfma_f32_16x16x32_bf16(af[m], bf[n],
                                                            acc[m][n], 0, 0, 0);
  }

  const int r0 = (lane >> 4) * 4, c0 = lane & 15;
  #pragma unroll
  for (int m = 0; m < 4; ++m) {
    #pragma unroll
    for (int n = 0; n < 4; ++n) {
      const int row = m0 + wr * 64 + m * 16 + r0;
      const int col = n0 + wc * 64 + n * 16 + c0;
      const float bv = bias[col];
      if (MODE == 0) {
        #pragma unroll
        for (int r = 0; r < 4; ++r)
          Cf[(size_t)(row + r) * N + col] = acc[m][n][r] + bv;
      } else {
        if (col < 2 * E_) {
          #pragma unroll
          for (int r = 0; r < 4; ++r)
            Cbf[(size_t)(row + r) * QKS + col] = f2bf(acc[m][n][r] + bv);
        } else {
          const int hd = col - 2 * E_;
          ushort4 o;
          o.x = f2bf(acc[m][n][0] + bv);
          o.y = f2bf(acc[m][n][1] + bv);
          o.z = f2bf(acc[m][n][2] + bv);
          o.w = f2bf(acc[m][n][3] + bv);
          *(ushort4*)&Vt[(((size_t)(row >> 11) * H_ + (hd >> 6)) * HD_ +
                          (hd & 63)) * (size_t)S_ + (row & 2047)] = o;
        }
      }
    }
  }
}

// ---------------- flash attention (causal), QBLK=64, KVBLK=64 ----------------
// qk [B][S][2048] bf16 (q at col 0, k at 1024), Vt [B*H][64][S] bf16
// out aout [B][S][E] bf16
__global__ __launch_bounds__(256) void flash_attn(
    const unsigned short* __restrict__ qk,
    const unsigned short* __restrict__ Vt,
    unsigned short* __restrict__ aout) {
  __shared__ __align__(16) unsigned short Ks[64 * 64];     // [k][d], XOR-swizzled
  __shared__ __align__(16) unsigned short Vs[64 * 64];     // [d][k], XOR-swizzled
  __shared__ __align__(16) unsigned short Ps[4][16 * 64];  // per-wave P, swizzled

  const int t = threadIdx.x, lane = t & 63, w = t >> 6;
  const int qt = 31 - blockIdx.x;        // longest blocks first
  const int bh = blockIdx.y;
  const int b = bh >> 4, h = bh & 15;
  const int lrow = lane & 15, lk = (lane >> 4) * 8;
  const int swl = (lrow & 7) << 3;
  const size_t basebs = (size_t)b * S_;

  // Q fragments resident in registers
  short8 qf[2];
  {
    const int qrow = qt * 64 + w * 16 + lrow;
    const unsigned short* qp = qk + (basebs + qrow) * QKS + h * HD_;
    qf[0] = *(const short8*)(qp + lk);
    qf[1] = *(const short8*)(qp + 32 + lk);
  }

  float m_r[4], l_r[4];
  f32x4 o_acc[4];
  const f32x4 z = {0.f, 0.f, 0.f, 0.f};
  #pragma unroll
  for (int r = 0; r < 4; ++r) { m_r[r] = -1e30f; l_r[r] = 0.f; }
  #pragma unroll
  for (int n = 0; n < 4; ++n) o_acc[n] = z;

  const int qrow_lane = qt * 64 + w * 16 + (lane >> 4) * 4;
  const int sr = t >> 3, scc = (t & 7) * 8;  // staging row / col-chunk

  for (int kt = 0; kt <= qt; ++kt) {
    const int k0 = kt * 64;
    __syncthreads();  // previous tile fully consumed
    // stage K[64][64] and V^T[64][64]; LDS dest linear, source pre-swizzled
    #pragma unroll
    for (int c = 0; c < 2; ++c) {
      const int r = sr + c * 32;
      const int gcol = scc ^ ((r & 7) << 3);
      gload16(qk + (basebs + k0 + r) * QKS + E_ + h * HD_ + gcol,
              &Ks[t * 8 + c * 2048]);
      gload16(Vt + ((size_t)bh * HD_ + r) * S_ + k0 + gcol,
              &Vs[t * 8 + c * 2048]);
    }
    __syncthreads();  // drains vmcnt -> tiles ready

    // QK^T: S[16 q][64 k] per wave
    f32x4 sc4[4];
    #pragma unroll
    for (int n = 0; n < 4; ++n) {
      const int rowb = (n * 16 + lrow) * 64;
      short8 kf0 = *(const short8*)&Ks[rowb + (lk ^ swl)];
      short8 kf1 = *(const short8*)&Ks[rowb + ((lk + 32) ^ swl)];
      sc4[n] = __builtin_amdgcn_mfma_f32_16x16x32_bf16(qf[0], kf0, z, 0, 0, 0);
      sc4[n] = __builtin_amdgcn_mfma_f32_16x16x32_bf16(qf[1], kf1, sc4[n], 0, 0, 0);
    }

    // online softmax; rows live in 16-lane groups
    #pragma unroll
    for (int r = 0; r < 4; ++r) {
      float s0 = sc4[0][r] * 0.125f;
      float s1 = sc4[1][r] * 0.125f;
      float s2 = sc4[2][r] * 0.125f;
      float s3 = sc4[3][r] * 0.125f;
      if (kt == qt) {  // diagonal tile: causal mask (block-uniform branch)
        const int qg = qrow_lane + r;
        if (k0 + lrow      > qg) s0 = -1e30f;
        if (k0 + 16 + lrow > qg) s1 = -1e30f;
        if (k0 + 32 + lrow > qg) s2 = -1e30f;
        if (k0 + 48 + lrow > qg) s3 = -1e30f;
      }
      float tm = fmaxf(fmaxf(s0, s1), fmaxf(s2, s3));
      #pragma unroll
      for (int off = 1; off < 16; off <<= 1)
        tm = fmaxf(tm, __shfl_xor(tm, off));
      const float mnew = fmaxf(m_r[r], tm);
      const float alpha = __expf(m_r[r] - mnew);
      const float p0 = __expf(s0 - mnew);
      const float p1 = __expf(s1 - mnew);
      const float p2 = __expf(s2 - mnew);
      const float p3 = __expf(s3 - mnew);
      m_r[r] = mnew;
      float ts = (p0 + p1) + (p2 + p3);
      #pragma unroll
      for (int off = 1; off < 16; off <<= 1)
        ts += __shfl_xor(ts, off);
      l_r[r] = l_r[r] * alpha + ts;
      #pragma unroll
      for (int n = 0; n < 4; ++n) o_acc[n][r] *= alpha;
      const int prow = (lane >> 4) * 4 + r;
      const int swp = (prow & 7) << 3;
      unsigned short* pr = &Ps[w][prow * 64];
      pr[lrow ^ swp]        = f2bf(p0);
      pr[(16 + lrow) ^ swp] = f2bf(p1);
      pr[(32 + lrow) ^ swp] = f2bf(p2);
      pr[(48 + lrow) ^ swp] = f2bf(p3);
    }

    // PV: O[16 q][64 d] += P[16][64] * V[64][64]
    short8 pa0 = *(const short8*)&Ps[w][lrow * 64 + (lk ^ swl)];
    short8 pa1 = *(const short8*)&Ps[w][lrow * 64 + ((lk + 32) ^ swl)];
    #pragma unroll
    for (int n = 0; n < 4; ++n) {
      const int rowb = (n * 16 + lrow) * 64;
      short8 vb0 = *(const short8*)&Vs[rowb + (lk ^ swl)];
      short8 vb1 = *(const short8*)&Vs[rowb + ((lk + 32) ^ swl)];
      o_acc[n] = __builtin_amdgcn_mfma_f32_16x16x32_bf16(pa0, vb0, o_acc[n], 0, 0, 0);
      o_acc[n] = __builtin_amdgcn_mfma_f32_16x16x32_bf16(pa1, vb1, o_acc[n], 0, 0, 0);
    }
  }

  // epilogue: normalize, store merged-head layout
  #pragma unroll
  for (int n = 0; n < 4; ++n) {
    #pragma unroll
    for (int r = 0; r < 4; ++r) {
      const int row = qrow_lane + r;
      aout[(basebs + row) * E_ + h * HD_ + n * 16 + lrow] =
          f2bf(o_acc[n][r] / l_r[r]);
    }
  }
}

extern "C" void kernel_launch(void* const* d_in, const int* in_sizes, int n_in,
                              void* d_out, int out_size, void* d_ws, size_t ws_size,
                              hipStream_t stream) {
  const float* X  = (const float*)d_in[0];
  const float* Wa = (const float*)d_in[1];
  const float* ba = (const float*)d_in[2];
  const float* Wp = (const float*)d_in[3];
  const float* bp = (const float*)d_in[4];
  float* out = (float*)d_out;

  char* ws = (char*)d_ws;
  unsigned short* Xb  = (unsigned short*)ws; ws += (size_t)M_ * E_ * 2;    // 8 MB
  unsigned short* WaT = (unsigned short*)ws; ws += (size_t)E3_ * E_ * 2;   // 6 MB
  unsigned short* WpT = (unsigned short*)ws; ws += (size_t)E_ * E_ * 2;    // 2 MB
  unsigned short* QK  = (unsigned short*)ws; ws += (size_t)M_ * QKS * 2;   // 16 MB
  unsigned short* Vt  = (unsigned short*)ws; ws += (size_t)M_ * E_ * 2;    // 8 MB
  unsigned short* AO  = (unsigned short*)ws; ws += (size_t)M_ * E_ * 2;    // 8 MB

  cvt_f32_bf16<<<(M_ * E_ / 4 + 255) / 256, 256, 0, stream>>>(X, Xb, M_ * E_);
  transpose_bf16<<<dim3(E3_ / 32, E_ / 32), 256, 0, stream>>>(Wa, WaT, E_, E3_);
  transpose_bf16<<<dim3(E_ / 32, E_ / 32), 256, 0, stream>>>(Wp, WpT, E_, E_);
  gemm_bt_bias<1><<<dim3(E3_ / 128, M_ / 128), 256, 0, stream>>>(
      Xb, WaT, ba, nullptr, QK, Vt, M_, E3_, E_);
  flash_attn<<<dim3(S_ / 64, B_ * H_), 256, 0, stream>>>(QK, Vt, AO);
  gemm_bt_bias<0><<<dim3(E_ / 128, M_ / 128), 256, 0, stream>>>(
      AO, WpT, bp, out, nullptr, nullptr, M_, E_, E_);
}

// Round 3
// 147.611 us; speedup vs baseline: 2.0664x; 1.4448x over previous
//
#include <hip/hip_runtime.h>
#include <hip/hip_bf16.h>

#define B_   2
#define S_   2048
#define E_   1024
#define H_   16
#define HD_  64
#define E3_  3072
#define M_   4096   // B*S
#define QKS  2048   // stride of QK buffer

using short8 = __attribute__((ext_vector_type(8))) short;
using f32x4  = __attribute__((ext_vector_type(4))) float;

__device__ __forceinline__ unsigned short f2bf(float f) {
  union { float f; unsigned v; } t; t.f = f;
  unsigned r = t.v + 0x7FFFu + ((t.v >> 16) & 1u);  // RNE
  return (unsigned short)(r >> 16);
}

__device__ __forceinline__ void gload16(const void* g, void* l) {
  __builtin_amdgcn_global_load_lds(
      (const __attribute__((address_space(1))) unsigned int*)g,
      (__attribute__((address_space(3))) unsigned int*)l, 16, 0, 0);
}

// ---------------- f32 -> bf16 convert ----------------
__global__ void cvt_f32_bf16(const float* __restrict__ in,
                             unsigned short* __restrict__ out, int n) {
  int i = (blockIdx.x * blockDim.x + threadIdx.x) * 4;
  if (i < n) {
    float4 v = *(const float4*)(in + i);
    ushort4 o;
    o.x = f2bf(v.x); o.y = f2bf(v.y); o.z = f2bf(v.z); o.w = f2bf(v.w);
    *(ushort4*)(out + i) = o;
  }
}

// ---------------- W [K][N] f32 -> WT [N][K] bf16 ----------------
__global__ void transpose_bf16(const float* __restrict__ W,
                               unsigned short* __restrict__ WT, int K, int N) {
  __shared__ float tile[32][33];
  int bn = blockIdx.x * 32, bk = blockIdx.y * 32;
  int tx = threadIdx.x & 31, ty = threadIdx.x >> 5;  // 32 x 8
  #pragma unroll
  for (int i = 0; i < 32; i += 8)
    tile[ty + i][tx] = W[(size_t)(bk + ty + i) * N + bn + tx];
  __syncthreads();
  #pragma unroll
  for (int i = 0; i < 32; i += 8)
    WT[(size_t)(bn + ty + i) * K + bk + tx] = f2bf(tile[tx][ty + i]);
}

// ---------------- 128x128 bf16 MFMA GEMM, B^T layout, fused bias ----------------
// MODE 0: f32 out, ldc = N.
// MODE 1: qkv split -> cols < 2048 as bf16 into Cbf (ldc 2048),
//         cols >= 2048 (the V block) transposed into Vt[bh][d][s].
template <int MODE>
__global__ __launch_bounds__(256) void gemm_bt_bias(
    const unsigned short* __restrict__ A,
    const unsigned short* __restrict__ BT,
    const float* __restrict__ bias,
    float* __restrict__ Cf,
    unsigned short* __restrict__ Cbf,
    unsigned short* __restrict__ Vt,
    int M, int N, int K) {
  __shared__ __align__(16) unsigned short As[128 * 32];
  __shared__ __align__(16) unsigned short Bs[128 * 32];
  const int t = threadIdx.x;
  const int lane = t & 63, w = t >> 6;
  const int wr = w >> 1, wc = w & 1;
  const int m0 = blockIdx.y * 128, n0 = blockIdx.x * 128;
  const int lrow = lane & 15, lk = (lane >> 4) * 8;
  const int ar = t >> 2, ac = (t & 3) * 8;  // staging row/col

  f32x4 acc[4][4];
  const f32x4 z = {0.f, 0.f, 0.f, 0.f};
  #pragma unroll
  for (int i = 0; i < 4; ++i)
    #pragma unroll
    for (int j = 0; j < 4; ++j) acc[i][j] = z;

  for (int k0 = 0; k0 < K; k0 += 32) {
    __syncthreads();
    #pragma unroll
    for (int i = 0; i < 2; ++i) {
      gload16(A  + (size_t)(m0 + i * 64 + ar) * K + k0 + ac,
              &As[(i * 64 + ar) * 32 + ac]);
      gload16(BT + (size_t)(n0 + i * 64 + ar) * K + k0 + ac,
              &Bs[(i * 64 + ar) * 32 + ac]);
    }
    __syncthreads();

    short8 af[4], bf[4];
    #pragma unroll
    for (int m = 0; m < 4; ++m)
      af[m] = *(const short8*)&As[(wr * 64 + m * 16 + lrow) * 32 + lk];
    #pragma unroll
    for (int n = 0; n < 4; ++n)
      bf[n] = *(const short8*)&Bs[(wc * 64 + n * 16 + lrow) * 32 + lk];
    #pragma unroll
    for (int m = 0; m < 4; ++m)
      #pragma unroll
      for (int n = 0; n < 4; ++n)
        acc[m][n] = __builtin_amdgcn_mfma_f32_16x16x32_bf16(af[m], bf[n],
                                                            acc[m][n], 0, 0, 0);
  }

  const int r0 = (lane >> 4) * 4, c0 = lane & 15;
  #pragma unroll
  for (int m = 0; m < 4; ++m) {
    #pragma unroll
    for (int n = 0; n < 4; ++n) {
      const int row = m0 + wr * 64 + m * 16 + r0;
      const int col = n0 + wc * 64 + n * 16 + c0;
      const float bv = bias[col];
      if (MODE == 0) {
        #pragma unroll
        for (int r = 0; r < 4; ++r)
          Cf[(size_t)(row + r) * N + col] = acc[m][n][r] + bv;
      } else {
        if (col < 2 * E_) {
          #pragma unroll
          for (int r = 0; r < 4; ++r)
            Cbf[(size_t)(row + r) * QKS + col] = f2bf(acc[m][n][r] + bv);
        } else {
          const int hd = col - 2 * E_;
          ushort4 o;
          o.x = f2bf(acc[m][n][0] + bv);
          o.y = f2bf(acc[m][n][1] + bv);
          o.z = f2bf(acc[m][n][2] + bv);
          o.w = f2bf(acc[m][n][3] + bv);
          *(ushort4*)&Vt[(((size_t)(row >> 11) * H_ + (hd >> 6)) * HD_ +
                          (hd & 63)) * (size_t)S_ + (row & 2047)] = o;
        }
      }
    }
  }
}

// ---------------- flash attention (causal), QBLK=64, KVBLK=64 ----------------
// Swapped-QK^T structure: per wave, S^T[k][q] so softmax is lane-local.
// qk [B][S][2048] bf16 (q at 0, k at 1024), Vt [B*H][64][S] bf16
__global__ __launch_bounds__(256) void flash_attn(
    const unsigned short* __restrict__ qk,
    const unsigned short* __restrict__ Vt,
    unsigned short* __restrict__ aout) {
  __shared__ __align__(16) unsigned short Ks[2][64 * 64];   // [k][d], swizzled
  __shared__ __align__(16) unsigned short Vs[2][64 * 64];   // [d][k], swizzled
  __shared__ __align__(16) unsigned short Ps[4][16 * 64];   // per-wave P[q][k]

  const int t = threadIdx.x, lane = t & 63, w = t >> 6;
  const int qt = 31 - blockIdx.x;        // longest blocks first
  const int bh = blockIdx.y;
  const int b = bh >> 4, h = bh & 15;
  const int lq = lane & 15;              // owned q (softmax) / A-row (PV)
  const int g  = lane >> 4;
  const int lk8 = g * 8;
  const int swzq = (lq & 7) << 3;
  const size_t basebs = (size_t)b * S_;
  const f32x4 z = {0.f, 0.f, 0.f, 0.f};

  // Q fragments (B-operand role): lane holds Q[q = w*16+lq][8g+j (+32)]
  short8 qf[2];
  {
    const int qrow = qt * 64 + w * 16 + lq;
    const unsigned short* qp = qk + (basebs + qrow) * QKS + h * HD_;
    qf[0] = *(const short8*)(qp + lk8);
    qf[1] = *(const short8*)(qp + 32 + lk8);
  }

  float m_q = -1e30f, l_q = 0.f;
  f32x4 o_acc[4];                        // O[q=4g+r][d = n*16+lq]
  #pragma unroll
  for (int n = 0; n < 4; ++n) o_acc[n] = z;

  const int sr = t >> 3, scc = (t & 7) * 8;  // staging row / col-chunk
  auto stage = [&](int buf, int kt) {
    const int k0 = kt * 64;
    #pragma unroll
    for (int c = 0; c < 2; ++c) {
      const int r = sr + c * 32;
      const int gcol = scc ^ ((r & 7) << 3);
      gload16(qk + (basebs + k0 + r) * QKS + E_ + h * HD_ + gcol,
              &Ks[buf][t * 8 + c * 2048]);
      gload16(Vt + ((size_t)bh * HD_ + r) * S_ + k0 + gcol,
              &Vs[buf][t * 8 + c * 2048]);
    }
  };

  stage(0, 0);
  __syncthreads();   // drains vmcnt -> tile 0 resident
  int cur = 0;

  for (int kt = 0; kt <= qt; ++kt) {
    if (kt < qt) stage(cur ^ 1, kt + 1);   // async prefetch next tile

    // QK^T swapped: st[f][r] = S[k = 16f+4g+r][q = lq] (pre-scale)
    f32x4 st[4];
    __builtin_amdgcn_s_setprio(1);
    #pragma unroll
    for (int f = 0; f < 4; ++f) {
      const int rowb = (f * 16 + lq) * 64;
      short8 kf0 = *(const short8*)&Ks[cur][rowb + (lk8 ^ swzq)];
      short8 kf1 = *(const short8*)&Ks[cur][rowb + ((lk8 + 32) ^ swzq)];
      st[f] = __builtin_amdgcn_mfma_f32_16x16x32_bf16(kf0, qf[0], z, 0, 0, 0);
      st[f] = __builtin_amdgcn_mfma_f32_16x16x32_bf16(kf1, qf[1], st[f], 0, 0, 0);
    }
    __builtin_amdgcn_s_setprio(0);

    float s[4][4];
    #pragma unroll
    for (int f = 0; f < 4; ++f)
      #pragma unroll
      for (int r = 0; r < 4; ++r)
        s[f][r] = st[f][r] * 0.125f;
    if (kt == qt) {  // diagonal: causal mask (block-uniform branch)
      const int qcol = w * 16 + lq;
      #pragma unroll
      for (int f = 0; f < 4; ++f)
        #pragma unroll
        for (int r = 0; r < 4; ++r)
          if (16 * f + 4 * g + r > qcol) s[f][r] = -1e30f;
    }

    // in-register tile max + 2-step cross-group reduce
    float t0 = fmaxf(fmaxf(s[0][0], s[0][1]), fmaxf(s[0][2], s[0][3]));
    float t1 = fmaxf(fmaxf(s[1][0], s[1][1]), fmaxf(s[1][2], s[1][3]));
    float t2 = fmaxf(fmaxf(s[2][0], s[2][1]), fmaxf(s[2][2], s[2][3]));
    float t3 = fmaxf(fmaxf(s[3][0], s[3][1]), fmaxf(s[3][2], s[3][3]));
    float tm = fmaxf(fmaxf(t0, t1), fmaxf(t2, t3));
    tm = fmaxf(tm, __shfl_xor(tm, 16));
    tm = fmaxf(tm, __shfl_xor(tm, 32));

    // defer-max: rescale only if some lane's tile-max exceeds m+6
    if (__ballot(tm > m_q + 6.0f)) {
      const float mnew = fmaxf(m_q, tm);
      const float alpha = __expf(m_q - mnew);
      m_q = mnew;
      l_q *= alpha;
      #pragma unroll
      for (int r = 0; r < 4; ++r) {
        const float ar = __shfl(alpha, 4 * g + r);   // alpha for o-row 4g+r
        #pragma unroll
        for (int n = 0; n < 4; ++n) o_acc[n][r] *= ar;
      }
    }

    // P = exp(S - m), packed bf16, per-lane partial sum
    float ts = 0.f;
    unsigned pw[4][2];
    #pragma unroll
    for (int f = 0; f < 4; ++f) {
      float p0 = __expf(s[f][0] - m_q);
      float p1 = __expf(s[f][1] - m_q);
      float p2 = __expf(s[f][2] - m_q);
      float p3 = __expf(s[f][3] - m_q);
      ts += (p0 + p1) + (p2 + p3);
      asm("v_cvt_pk_bf16_f32 %0, %1, %2" : "=v"(pw[f][0]) : "v"(p0), "v"(p1));
      asm("v_cvt_pk_bf16_f32 %0, %1, %2" : "=v"(pw[f][1]) : "v"(p2), "v"(p3));
    }
    ts += __shfl_xor(ts, 16);
    ts += __shfl_xor(ts, 32);
    l_q += ts;

    // scatter P to Ps[q][k] (swizzled, u32 writes)
    {
      unsigned short* pr = &Ps[w][lq * 64];
      #pragma unroll
      for (int f = 0; f < 4; ++f) {
        *(unsigned*)&pr[(16 * f + 4 * g) ^ swzq]       = pw[f][0];
        *(unsigned*)&pr[((16 * f + 4 * g + 2) ^ swzq)] = pw[f][1];
      }
    }

    // PV: O[16 q][64 d] += P[16][64] * V[64][64]
    short8 pa0 = *(const short8*)&Ps[w][lq * 64 + (lk8 ^ swzq)];
    short8 pa1 = *(const short8*)&Ps[w][lq * 64 + ((lk8 + 32) ^ swzq)];
    __builtin_amdgcn_s_setprio(1);
    #pragma unroll
    for (int n = 0; n < 4; ++n) {
      const int rowb = (n * 16 + lq) * 64;
      short8 vb0 = *(const short8*)&Vs[cur][rowb + (lk8 ^ swzq)];
      short8 vb1 = *(const short8*)&Vs[cur][rowb + ((lk8 + 32) ^ swzq)];
      o_acc[n] = __builtin_amdgcn_mfma_f32_16x16x32_bf16(pa0, vb0, o_acc[n], 0, 0, 0);
      o_acc[n] = __builtin_amdgcn_mfma_f32_16x16x32_bf16(pa1, vb1, o_acc[n], 0, 0, 0);
    }
    __builtin_amdgcn_s_setprio(0);

    __syncthreads();   // drains prefetch into cur^1; all waves done with cur
    cur ^= 1;
  }

  // epilogue: normalize, store merged-head layout
  const int qbase = qt * 64 + w * 16 + 4 * g;
  #pragma unroll
  for (int r = 0; r < 4; ++r) {
    const float lr = __shfl(l_q, 4 * g + r);
    const float inv = 1.0f / lr;
    const int row = qbase + r;
    #pragma unroll
    for (int n = 0; n < 4; ++n)
      aout[(basebs + row) * E_ + h * HD_ + n * 16 + lq] =
          f2bf(o_acc[n][r] * inv);
  }
}

extern "C" void kernel_launch(void* const* d_in, const int* in_sizes, int n_in,
                              void* d_out, int out_size, void* d_ws, size_t ws_size,
                              hipStream_t stream) {
  const float* X  = (const float*)d_in[0];
  const float* Wa = (const float*)d_in[1];
  const float* ba = (const float*)d_in[2];
  const float* Wp = (const float*)d_in[3];
  const float* bp = (const float*)d_in[4];
  float* out = (float*)d_out;

  char* ws = (char*)d_ws;
  unsigned short* Xb  = (unsigned short*)ws; ws += (size_t)M_ * E_ * 2;    // 8 MB
  unsigned short* WaT = (unsigned short*)ws; ws += (size_t)E3_ * E_ * 2;   // 6 MB
  unsigned short* WpT = (unsigned short*)ws; ws += (size_t)E_ * E_ * 2;    // 2 MB
  unsigned short* QK  = (unsigned short*)ws; ws += (size_t)M_ * QKS * 2;   // 16 MB
  unsigned short* Vt  = (unsigned short*)ws; ws += (size_t)M_ * E_ * 2;    // 8 MB
  unsigned short* AO  = (unsigned short*)ws; ws += (size_t)M_ * E_ * 2;    // 8 MB

  cvt_f32_bf16<<<(M_ * E_ / 4 + 255) / 256, 256, 0, stream>>>(X, Xb, M_ * E_);
  transpose_bf16<<<dim3(E3_ / 32, E_ / 32), 256, 0, stream>>>(Wa, WaT, E_, E3_);
  transpose_bf16<<<dim3(E_ / 32, E_ / 32), 256, 0, stream>>>(Wp, WpT, E_, E_);
  gemm_bt_bias<1><<<dim3(E3_ / 128, M_ / 128), 256, 0, stream>>>(
      Xb, WaT, ba, nullptr, QK, Vt, M_, E3_, E_);
  flash_attn<<<dim3(S_ / 64, B_ * H_), 256, 0, stream>>>(QK, Vt, AO);
  gemm_bt_bias<0><<<dim3(E_ / 128, M_ / 128), 256, 0, stream>>>(
      AO, WpT, bp, out, nullptr, nullptr, M_, E_, E_);
}

// Round 4
// 127.972 us; speedup vs baseline: 2.3835x; 1.1535x over previous
//
#include <hip/hip_runtime.h>
#include <hip/hip_bf16.h>

#define B_   2
#define S_   2048
#define E_   1024
#define H_   16
#define HD_  64
#define E3_  3072
#define M_   4096   // B*S
#define QKS  2048   // stride of QK buffer

using short8 = __attribute__((ext_vector_type(8))) short;
using f32x4  = __attribute__((ext_vector_type(4))) float;

__device__ __forceinline__ unsigned short f2bf(float f) {
  union { float f; unsigned v; } t; t.f = f;
  unsigned r = t.v + 0x7FFFu + ((t.v >> 16) & 1u);  // RNE
  return (unsigned short)(r >> 16);
}

__device__ __forceinline__ void gload16(const void* g, void* l) {
  __builtin_amdgcn_global_load_lds(
      (const __attribute__((address_space(1))) unsigned int*)g,
      (__attribute__((address_space(3))) unsigned int*)l, 16, 0, 0);
}

// ---------------- f32 -> bf16 convert ----------------
__global__ void cvt_f32_bf16(const float* __restrict__ in,
                             unsigned short* __restrict__ out, int n) {
  int i = (blockIdx.x * blockDim.x + threadIdx.x) * 4;
  if (i < n) {
    float4 v = *(const float4*)(in + i);
    ushort4 o;
    o.x = f2bf(v.x); o.y = f2bf(v.y); o.z = f2bf(v.z); o.w = f2bf(v.w);
    *(ushort4*)(out + i) = o;
  }
}

// ---------------- W [K][N] f32 -> WT [N][K] bf16 ----------------
__global__ void transpose_bf16(const float* __restrict__ W,
                               unsigned short* __restrict__ WT, int K, int N) {
  __shared__ float tile[32][33];
  int bn = blockIdx.x * 32, bk = blockIdx.y * 32;
  int tx = threadIdx.x & 31, ty = threadIdx.x >> 5;  // 32 x 8
  #pragma unroll
  for (int i = 0; i < 32; i += 8)
    tile[ty + i][tx] = W[(size_t)(bk + ty + i) * N + bn + tx];
  __syncthreads();
  #pragma unroll
  for (int i = 0; i < 32; i += 8)
    WT[(size_t)(bn + ty + i) * K + bk + tx] = f2bf(tile[tx][ty + i]);
}

// ---------------- 128x128 bf16 MFMA GEMM, B^T layout, fused bias ----------------
// MODE 0: f32 out, ldc = N.
// MODE 1: qkv split -> cols < 2048 as bf16 into Cbf (ldc 2048),
//         cols >= 2048 (the V block) transposed into Vt[bh][d][s].
template <int MODE>
__global__ __launch_bounds__(256) void gemm_bt_bias(
    const unsigned short* __restrict__ A,
    const unsigned short* __restrict__ BT,
    const float* __restrict__ bias,
    float* __restrict__ Cf,
    unsigned short* __restrict__ Cbf,
    unsigned short* __restrict__ Vt,
    int M, int N, int K) {
  __shared__ __align__(16) unsigned short As[128 * 32];
  __shared__ __align__(16) unsigned short Bs[128 * 32];
  const int t = threadIdx.x;
  const int lane = t & 63, w = t >> 6;
  const int wr = w >> 1, wc = w & 1;
  const int m0 = blockIdx.y * 128, n0 = blockIdx.x * 128;
  const int lrow = lane & 15, lk = (lane >> 4) * 8;
  const int ar = t >> 2, ac = (t & 3) * 8;  // staging row/col

  f32x4 acc[4][4];
  const f32x4 z = {0.f, 0.f, 0.f, 0.f};
  #pragma unroll
  for (int i = 0; i < 4; ++i)
    #pragma unroll
    for (int j = 0; j < 4; ++j) acc[i][j] = z;

  for (int k0 = 0; k0 < K; k0 += 32) {
    __syncthreads();
    #pragma unroll
    for (int i = 0; i < 2; ++i) {
      gload16(A  + (size_t)(m0 + i * 64 + ar) * K + k0 + ac,
              &As[(i * 64 + ar) * 32 + ac]);
      gload16(BT + (size_t)(n0 + i * 64 + ar) * K + k0 + ac,
              &Bs[(i * 64 + ar) * 32 + ac]);
    }
    __syncthreads();

    short8 af[4], bf[4];
    #pragma unroll
    for (int m = 0; m < 4; ++m)
      af[m] = *(const short8*)&As[(wr * 64 + m * 16 + lrow) * 32 + lk];
    #pragma unroll
    for (int n = 0; n < 4; ++n)
      bf[n] = *(const short8*)&Bs[(wc * 64 + n * 16 + lrow) * 32 + lk];
    #pragma unroll
    for (int m = 0; m < 4; ++m)
      #pragma unroll
      for (int n = 0; n < 4; ++n)
        acc[m][n] = __builtin_amdgcn_mfma_f32_16x16x32_bf16(af[m], bf[n],
                                                            acc[m][n], 0, 0, 0);
  }

  const int r0 = (lane >> 4) * 4, c0 = lane & 15;
  #pragma unroll
  for (int m = 0; m < 4; ++m) {
    #pragma unroll
    for (int n = 0; n < 4; ++n) {
      const int row = m0 + wr * 64 + m * 16 + r0;
      const int col = n0 + wc * 64 + n * 16 + c0;
      const float bv = bias[col];
      if (MODE == 0) {
        #pragma unroll
        for (int r = 0; r < 4; ++r)
          Cf[(size_t)(row + r) * N + col] = acc[m][n][r] + bv;
      } else {
        if (col < 2 * E_) {
          #pragma unroll
          for (int r = 0; r < 4; ++r)
            Cbf[(size_t)(row + r) * QKS + col] = f2bf(acc[m][n][r] + bv);
        } else {
          const int hd = col - 2 * E_;
          ushort4 o;
          o.x = f2bf(acc[m][n][0] + bv);
          o.y = f2bf(acc[m][n][1] + bv);
          o.z = f2bf(acc[m][n][2] + bv);
          o.w = f2bf(acc[m][n][3] + bv);
          *(ushort4*)&Vt[(((size_t)(row >> 11) * H_ + (hd >> 6)) * HD_ +
                          (hd & 63)) * (size_t)S_ + (row & 2047)] = o;
        }
      }
    }
  }
}

// ---------------- flash attention (causal), QBLK=64, KVBLK=64 ----------------
// Swapped-QK^T structure: per wave, S^T[k][q] so softmax is lane-local.
// qk [B][S][2048] bf16 (q at 0, k at 1024), Vt [B*H][64][S] bf16
// Work-balance: blockIdx.x = bh (uniform), blockIdx.y -> qt via a balanced
// partition {i, 15-i, 16+i, 31-i} (each CU-resident group sums to 66 tiles).
__global__ __launch_bounds__(256) void flash_attn(
    const unsigned short* __restrict__ qk,
    const unsigned short* __restrict__ Vt,
    unsigned short* __restrict__ aout) {
  __shared__ __align__(16) unsigned short Ks[2][64 * 64];   // [k][d], swizzled
  __shared__ __align__(16) unsigned short Vs[2][64 * 64];   // [d][k], swizzled
  __shared__ __align__(16) unsigned short Ps[4][16 * 64];   // per-wave P[q][k]

  const int t = threadIdx.x, lane = t & 63, w = t >> 6;
  const int bh = blockIdx.x;
  const int yy = blockIdx.y;
  const int pi = yy & 7, pv = yy >> 3;
  int qt;
  switch (pv) {
    case 0:  qt = pi;      break;
    case 1:  qt = 15 - pi; break;
    case 2:  qt = 16 + pi; break;
    default: qt = 31 - pi; break;
  }
  const int b = bh >> 4, h = bh & 15;
  const int lq = lane & 15;              // owned q (softmax) / A-row (PV)
  const int g  = lane >> 4;
  const int lk8 = g * 8;
  const int swzq = (lq & 7) << 3;
  const size_t basebs = (size_t)b * S_;
  const f32x4 z = {0.f, 0.f, 0.f, 0.f};

  // Q fragments (B-operand role): lane holds Q[q = w*16+lq][8g+j (+32)]
  short8 qf[2];
  {
    const int qrow = qt * 64 + w * 16 + lq;
    const unsigned short* qp = qk + (basebs + qrow) * QKS + h * HD_;
    qf[0] = *(const short8*)(qp + lk8);
    qf[1] = *(const short8*)(qp + 32 + lk8);
  }

  float m_q = -1e30f, l_q = 0.f;
  f32x4 o_acc[4];                        // O[q=4g+r][d = n*16+lq]
  #pragma unroll
  for (int n = 0; n < 4; ++n) o_acc[n] = z;

  const int sr = t >> 3, scc = (t & 7) * 8;  // staging row / col-chunk
  auto stage = [&](int buf, int kt) {
    const int k0 = kt * 64;
    #pragma unroll
    for (int c = 0; c < 2; ++c) {
      const int r = sr + c * 32;
      const int gcol = scc ^ ((r & 7) << 3);
      gload16(qk + (basebs + k0 + r) * QKS + E_ + h * HD_ + gcol,
              &Ks[buf][t * 8 + c * 2048]);
      gload16(Vt + ((size_t)bh * HD_ + r) * S_ + k0 + gcol,
              &Vs[buf][t * 8 + c * 2048]);
    }
  };

  stage(0, 0);
  __syncthreads();   // drains vmcnt -> tile 0 resident
  int cur = 0;

  for (int kt = 0; kt <= qt; ++kt) {
    if (kt < qt) stage(cur ^ 1, kt + 1);   // async prefetch next tile

    // QK^T swapped: st[f][r] = S[k = 16f+4g+r][q = lq] (pre-scale)
    f32x4 st[4];
    __builtin_amdgcn_s_setprio(1);
    #pragma unroll
    for (int f = 0; f < 4; ++f) {
      const int rowb = (f * 16 + lq) * 64;
      short8 kf0 = *(const short8*)&Ks[cur][rowb + (lk8 ^ swzq)];
      short8 kf1 = *(const short8*)&Ks[cur][rowb + ((lk8 + 32) ^ swzq)];
      st[f] = __builtin_amdgcn_mfma_f32_16x16x32_bf16(kf0, qf[0], z, 0, 0, 0);
      st[f] = __builtin_amdgcn_mfma_f32_16x16x32_bf16(kf1, qf[1], st[f], 0, 0, 0);
    }
    __builtin_amdgcn_s_setprio(0);

    float s[4][4];
    #pragma unroll
    for (int f = 0; f < 4; ++f)
      #pragma unroll
      for (int r = 0; r < 4; ++r)
        s[f][r] = st[f][r] * 0.125f;
    if (kt == qt) {  // diagonal: causal mask (block-uniform branch)
      const int qcol = w * 16 + lq;
      #pragma unroll
      for (int f = 0; f < 4; ++f)
        #pragma unroll
        for (int r = 0; r < 4; ++r)
          if (16 * f + 4 * g + r > qcol) s[f][r] = -1e30f;
    }

    // in-register tile max + 2-step cross-group reduce
    float t0 = fmaxf(fmaxf(s[0][0], s[0][1]), fmaxf(s[0][2], s[0][3]));
    float t1 = fmaxf(fmaxf(s[1][0], s[1][1]), fmaxf(s[1][2], s[1][3]));
    float t2 = fmaxf(fmaxf(s[2][0], s[2][1]), fmaxf(s[2][2], s[2][3]));
    float t3 = fmaxf(fmaxf(s[3][0], s[3][1]), fmaxf(s[3][2], s[3][3]));
    float tm = fmaxf(fmaxf(t0, t1), fmaxf(t2, t3));
    tm = fmaxf(tm, __shfl_xor(tm, 16));
    tm = fmaxf(tm, __shfl_xor(tm, 32));

    // defer-max: rescale only if some lane's tile-max exceeds m+6
    if (__ballot(tm > m_q + 6.0f)) {
      const float mnew = fmaxf(m_q, tm);
      const float alpha = __expf(m_q - mnew);
      m_q = mnew;
      l_q *= alpha;
      #pragma unroll
      for (int r = 0; r < 4; ++r) {
        const float ar = __shfl(alpha, 4 * g + r);   // alpha for o-row 4g+r
        #pragma unroll
        for (int n = 0; n < 4; ++n) o_acc[n][r] *= ar;
      }
    }

    // P = exp(S - m), packed bf16, per-lane partial sum
    float ts = 0.f;
    unsigned pw[4][2];
    #pragma unroll
    for (int f = 0; f < 4; ++f) {
      float p0 = __expf(s[f][0] - m_q);
      float p1 = __expf(s[f][1] - m_q);
      float p2 = __expf(s[f][2] - m_q);
      float p3 = __expf(s[f][3] - m_q);
      ts += (p0 + p1) + (p2 + p3);
      asm("v_cvt_pk_bf16_f32 %0, %1, %2" : "=v"(pw[f][0]) : "v"(p0), "v"(p1));
      asm("v_cvt_pk_bf16_f32 %0, %1, %2" : "=v"(pw[f][1]) : "v"(p2), "v"(p3));
    }
    ts += __shfl_xor(ts, 16);
    ts += __shfl_xor(ts, 32);
    l_q += ts;

    // scatter P to Ps[q][k] (swizzled, u32 writes)
    {
      unsigned short* pr = &Ps[w][lq * 64];
      #pragma unroll
      for (int f = 0; f < 4; ++f) {
        *(unsigned*)&pr[(16 * f + 4 * g) ^ swzq]       = pw[f][0];
        *(unsigned*)&pr[((16 * f + 4 * g + 2) ^ swzq)] = pw[f][1];
      }
    }

    // PV: O[16 q][64 d] += P[16][64] * V[64][64]
    short8 pa0 = *(const short8*)&Ps[w][lq * 64 + (lk8 ^ swzq)];
    short8 pa1 = *(const short8*)&Ps[w][lq * 64 + ((lk8 + 32) ^ swzq)];
    __builtin_amdgcn_s_setprio(1);
    #pragma unroll
    for (int n = 0; n < 4; ++n) {
      const int rowb = (n * 16 + lq) * 64;
      short8 vb0 = *(const short8*)&Vs[cur][rowb + (lk8 ^ swzq)];
      short8 vb1 = *(const short8*)&Vs[cur][rowb + ((lk8 + 32) ^ swzq)];
      o_acc[n] = __builtin_amdgcn_mfma_f32_16x16x32_bf16(pa0, vb0, o_acc[n], 0, 0, 0);
      o_acc[n] = __builtin_amdgcn_mfma_f32_16x16x32_bf16(pa1, vb1, o_acc[n], 0, 0, 0);
    }
    __builtin_amdgcn_s_setprio(0);

    __syncthreads();   // drains prefetch into cur^1; all waves done with cur
    cur ^= 1;
  }

  // epilogue: normalize, store merged-head layout
  const int qbase = qt * 64 + w * 16 + 4 * g;
  #pragma unroll
  for (int r = 0; r < 4; ++r) {
    const float lr = __shfl(l_q, 4 * g + r);
    const float inv = 1.0f / lr;
    const int row = qbase + r;
    #pragma unroll
    for (int n = 0; n < 4; ++n)
      aout[(basebs + row) * E_ + h * HD_ + n * 16 + lq] =
          f2bf(o_acc[n][r] * inv);
  }
}

extern "C" void kernel_launch(void* const* d_in, const int* in_sizes, int n_in,
                              void* d_out, int out_size, void* d_ws, size_t ws_size,
                              hipStream_t stream) {
  const float* X  = (const float*)d_in[0];
  const float* Wa = (const float*)d_in[1];
  const float* ba = (const float*)d_in[2];
  const float* Wp = (const float*)d_in[3];
  const float* bp = (const float*)d_in[4];
  float* out = (float*)d_out;

  char* ws = (char*)d_ws;
  unsigned short* Xb  = (unsigned short*)ws; ws += (size_t)M_ * E_ * 2;    // 8 MB
  unsigned short* WaT = (unsigned short*)ws; ws += (size_t)E3_ * E_ * 2;   // 6 MB
  unsigned short* WpT = (unsigned short*)ws; ws += (size_t)E_ * E_ * 2;    // 2 MB
  unsigned short* QK  = (unsigned short*)ws; ws += (size_t)M_ * QKS * 2;   // 16 MB
  unsigned short* Vt  = (unsigned short*)ws; ws += (size_t)M_ * E_ * 2;    // 8 MB
  unsigned short* AO  = (unsigned short*)ws; ws += (size_t)M_ * E_ * 2;    // 8 MB

  cvt_f32_bf16<<<(M_ * E_ / 4 + 255) / 256, 256, 0, stream>>>(X, Xb, M_ * E_);
  transpose_bf16<<<dim3(E3_ / 32, E_ / 32), 256, 0, stream>>>(Wa, WaT, E_, E3_);
  transpose_bf16<<<dim3(E_ / 32, E_ / 32), 256, 0, stream>>>(Wp, WpT, E_, E_);
  gemm_bt_bias<1><<<dim3(E3_ / 128, M_ / 128), 256, 0, stream>>>(
      Xb, WaT, ba, nullptr, QK, Vt, M_, E3_, E_);
  flash_attn<<<dim3(B_ * H_, S_ / 64), 256, 0, stream>>>(QK, Vt, AO);
  gemm_bt_bias<0><<<dim3(E_ / 128, M_ / 128), 256, 0, stream>>>(
      AO, WpT, bp, out, nullptr, nullptr, M_, E_, E_);
}

// Round 5
// 125.501 us; speedup vs baseline: 2.4305x; 1.0197x over previous
//
#include <hip/hip_runtime.h>
#include <hip/hip_bf16.h>

#define B_   2
#define S_   2048
#define E_   1024
#define H_   16
#define HD_  64
#define E3_  3072
#define M_   4096   // B*S
#define QKS  2048   // stride of QK buffer
#define QSC  0.1803368801111f   // 0.125 * log2(e): Q pre-scale, exp2 domain

using short8 = __attribute__((ext_vector_type(8))) short;
using f32x4  = __attribute__((ext_vector_type(4))) float;

__device__ __forceinline__ unsigned short f2bf(float f) {
  union { float f; unsigned v; } t; t.f = f;
  unsigned r = t.v + 0x7FFFu + ((t.v >> 16) & 1u);  // RNE
  return (unsigned short)(r >> 16);
}

__device__ __forceinline__ float max3f(float a, float b, float c) {
  return fmaxf(fmaxf(a, b), c);   // fuses to v_max3_f32
}

__device__ __forceinline__ float exp2_fast(float x) {
  float r;
  asm("v_exp_f32 %0, %1" : "=v"(r) : "v"(x));
  return r;
}

__device__ __forceinline__ void gload16(const void* g, void* l) {
  __builtin_amdgcn_global_load_lds(
      (const __attribute__((address_space(1))) unsigned int*)g,
      (__attribute__((address_space(3))) unsigned int*)l, 16, 0, 0);
}

// ---------------- f32 -> bf16 convert ----------------
__global__ void cvt_f32_bf16(const float* __restrict__ in,
                             unsigned short* __restrict__ out, int n) {
  int i = (blockIdx.x * blockDim.x + threadIdx.x) * 4;
  if (i < n) {
    float4 v = *(const float4*)(in + i);
    ushort4 o;
    o.x = f2bf(v.x); o.y = f2bf(v.y); o.z = f2bf(v.z); o.w = f2bf(v.w);
    *(ushort4*)(out + i) = o;
  }
}

// ---------------- W [K][N] f32 -> WT [N][K] bf16 ----------------
__global__ void transpose_bf16(const float* __restrict__ W,
                               unsigned short* __restrict__ WT, int K, int N) {
  __shared__ float tile[32][33];
  int bn = blockIdx.x * 32, bk = blockIdx.y * 32;
  int tx = threadIdx.x & 31, ty = threadIdx.x >> 5;  // 32 x 8
  #pragma unroll
  for (int i = 0; i < 32; i += 8)
    tile[ty + i][tx] = W[(size_t)(bk + ty + i) * N + bn + tx];
  __syncthreads();
  #pragma unroll
  for (int i = 0; i < 32; i += 8)
    WT[(size_t)(bn + ty + i) * K + bk + tx] = f2bf(tile[tx][ty + i]);
}

// ---------------- 128x128 bf16 MFMA GEMM, B^T layout, fused bias ----------------
// MODE 0: f32 out, ldc = N.
// MODE 1: qkv split -> Q cols (<1024) pre-scaled by QSC, bf16 into Cbf;
//         K cols (1024..2047) bf16 into Cbf; V cols (>=2048) transposed
//         into Vt[bh][d][s].
template <int MODE>
__global__ __launch_bounds__(256) void gemm_bt_bias(
    const unsigned short* __restrict__ A,
    const unsigned short* __restrict__ BT,
    const float* __restrict__ bias,
    float* __restrict__ Cf,
    unsigned short* __restrict__ Cbf,
    unsigned short* __restrict__ Vt,
    int M, int N, int K) {
  __shared__ __align__(16) unsigned short As[128 * 32];
  __shared__ __align__(16) unsigned short Bs[128 * 32];
  const int t = threadIdx.x;
  const int lane = t & 63, w = t >> 6;
  const int wr = w >> 1, wc = w & 1;
  const int m0 = blockIdx.y * 128, n0 = blockIdx.x * 128;
  const int lrow = lane & 15, lk = (lane >> 4) * 8;
  const int ar = t >> 2, ac = (t & 3) * 8;  // staging row/col

  f32x4 acc[4][4];
  const f32x4 z = {0.f, 0.f, 0.f, 0.f};
  #pragma unroll
  for (int i = 0; i < 4; ++i)
    #pragma unroll
    for (int j = 0; j < 4; ++j) acc[i][j] = z;

  for (int k0 = 0; k0 < K; k0 += 32) {
    __syncthreads();
    #pragma unroll
    for (int i = 0; i < 2; ++i) {
      gload16(A  + (size_t)(m0 + i * 64 + ar) * K + k0 + ac,
              &As[(i * 64 + ar) * 32 + ac]);
      gload16(BT + (size_t)(n0 + i * 64 + ar) * K + k0 + ac,
              &Bs[(i * 64 + ar) * 32 + ac]);
    }
    __syncthreads();

    short8 af[4], bf[4];
    #pragma unroll
    for (int m = 0; m < 4; ++m)
      af[m] = *(const short8*)&As[(wr * 64 + m * 16 + lrow) * 32 + lk];
    #pragma unroll
    for (int n = 0; n < 4; ++n)
      bf[n] = *(const short8*)&Bs[(wc * 64 + n * 16 + lrow) * 32 + lk];
    #pragma unroll
    for (int m = 0; m < 4; ++m)
      #pragma unroll
      for (int n = 0; n < 4; ++n)
        acc[m][n] = __builtin_amdgcn_mfma_f32_16x16x32_bf16(af[m], bf[n],
                                                            acc[m][n], 0, 0, 0);
  }

  const int r0 = (lane >> 4) * 4, c0 = lane & 15;
  #pragma unroll
  for (int m = 0; m < 4; ++m) {
    #pragma unroll
    for (int n = 0; n < 4; ++n) {
      const int row = m0 + wr * 64 + m * 16 + r0;
      const int col = n0 + wc * 64 + n * 16 + c0;
      const float bv = bias[col];
      if (MODE == 0) {
        #pragma unroll
        for (int r = 0; r < 4; ++r)
          Cf[(size_t)(row + r) * N + col] = acc[m][n][r] + bv;
      } else {
        if (col < 2 * E_) {
          const float sc = (col < E_) ? QSC : 1.0f;  // uniform per 16-col block
          #pragma unroll
          for (int r = 0; r < 4; ++r)
            Cbf[(size_t)(row + r) * QKS + col] = f2bf((acc[m][n][r] + bv) * sc);
        } else {
          const int hd = col - 2 * E_;
          ushort4 o;
          o.x = f2bf(acc[m][n][0] + bv);
          o.y = f2bf(acc[m][n][1] + bv);
          o.z = f2bf(acc[m][n][2] + bv);
          o.w = f2bf(acc[m][n][3] + bv);
          *(ushort4*)&Vt[(((size_t)(row >> 11) * H_ + (hd >> 6)) * HD_ +
                          (hd & 63)) * (size_t)S_ + (row & 2047)] = o;
        }
      }
    }
  }
}

// ---------------- flash attention (causal), QBLK=64, KVBLK=64 ----------------
// Swapped-QK^T structure: per wave, S^T[k][q] so softmax is lane-local.
// Q pre-scaled by 0.125*log2e -> scores in exp2 domain (p = exp2(s-m)).
// qk [B][S][2048] bf16 (q at 0, k at 1024), Vt [B*H][64][S] bf16
// Work-balance: blockIdx.x = bh (uniform), blockIdx.y -> qt via a balanced
// partition {i, 15-i, 16+i, 31-i} (each CU-resident group sums to 66 tiles).
__global__ __launch_bounds__(256) void flash_attn(
    const unsigned short* __restrict__ qk,
    const unsigned short* __restrict__ Vt,
    unsigned short* __restrict__ aout) {
  __shared__ __align__(16) unsigned short Ks[2][64 * 64];   // [k][d], swizzled
  __shared__ __align__(16) unsigned short Vs[2][64 * 64];   // [d][k], swizzled
  __shared__ __align__(16) unsigned short Ps[4][16 * 64];   // per-wave P[q][k]

  const int t = threadIdx.x, lane = t & 63, w = t >> 6;
  const int bh = blockIdx.x;
  const int yy = blockIdx.y;
  const int pi = yy & 7, pv = yy >> 3;
  int qt;
  switch (pv) {
    case 0:  qt = pi;      break;
    case 1:  qt = 15 - pi; break;
    case 2:  qt = 16 + pi; break;
    default: qt = 31 - pi; break;
  }
  const int b = bh >> 4, h = bh & 15;
  const int lq = lane & 15;              // owned q (softmax) / A-row (PV)
  const int g  = lane >> 4;
  const int lk8 = g * 8;
  const int swzq = (lq & 7) << 3;
  const size_t basebs = (size_t)b * S_;
  const f32x4 z = {0.f, 0.f, 0.f, 0.f};

  // Q fragments (B-operand role): lane holds Q[q = w*16+lq][8g+j (+32)]
  short8 qf[2];
  {
    const int qrow = qt * 64 + w * 16 + lq;
    const unsigned short* qp = qk + (basebs + qrow) * QKS + h * HD_;
    qf[0] = *(const short8*)(qp + lk8);
    qf[1] = *(const short8*)(qp + 32 + lk8);
  }

  float m_q = -1e30f, l_q = 0.f;
  f32x4 o_acc[4];                        // O[q=4g+r][d = n*16+lq]
  #pragma unroll
  for (int n = 0; n < 4; ++n) o_acc[n] = z;

  const int sr = t >> 3, scc = (t & 7) * 8;  // staging row / col-chunk
  auto stage = [&](int buf, int kt) {
    const int k0 = kt * 64;
    #pragma unroll
    for (int c = 0; c < 2; ++c) {
      const int r = sr + c * 32;
      const int gcol = scc ^ ((r & 7) << 3);
      gload16(qk + (basebs + k0 + r) * QKS + E_ + h * HD_ + gcol,
              &Ks[buf][t * 8 + c * 2048]);
      gload16(Vt + ((size_t)bh * HD_ + r) * S_ + k0 + gcol,
              &Vs[buf][t * 8 + c * 2048]);
    }
  };

  stage(0, 0);
  __syncthreads();   // drains vmcnt -> tile 0 resident
  int cur = 0;

  for (int kt = 0; kt <= qt; ++kt) {
    if (kt < qt) stage(cur ^ 1, kt + 1);   // async prefetch next tile

    // QK^T swapped: st[f][r] = S[k = 16f+4g+r][q = lq] (exp2-domain scores)
    f32x4 st[4];
    __builtin_amdgcn_s_setprio(1);
    #pragma unroll
    for (int f = 0; f < 4; ++f) {
      const int rowb = (f * 16 + lq) * 64;
      short8 kf0 = *(const short8*)&Ks[cur][rowb + (lk8 ^ swzq)];
      short8 kf1 = *(const short8*)&Ks[cur][rowb + ((lk8 + 32) ^ swzq)];
      st[f] = __builtin_amdgcn_mfma_f32_16x16x32_bf16(kf0, qf[0], z, 0, 0, 0);
      st[f] = __builtin_amdgcn_mfma_f32_16x16x32_bf16(kf1, qf[1], st[f], 0, 0, 0);
    }
    __builtin_amdgcn_s_setprio(0);

    if (kt == qt) {  // diagonal: causal mask (block-uniform branch)
      const int qcol = w * 16 + lq;
      #pragma unroll
      for (int f = 0; f < 4; ++f)
        #pragma unroll
        for (int r = 0; r < 4; ++r)
          if (16 * f + 4 * g + r > qcol) st[f][r] = -1e30f;
    }

    // tile max: 8-op max3 tree + 2-step cross-group reduce
    float a0 = max3f(st[0][0], st[0][1], st[0][2]);
    float a1 = max3f(st[0][3], st[1][0], st[1][1]);
    float a2 = max3f(st[1][2], st[1][3], st[2][0]);
    float a3 = max3f(st[2][1], st[2][2], st[2][3]);
    float a4 = max3f(st[3][0], st[3][1], st[3][2]);
    float tm = fmaxf(max3f(a0, a1, a2), max3f(a3, a4, st[3][3]));
    tm = fmaxf(tm, __shfl_xor(tm, 16));
    tm = fmaxf(tm, __shfl_xor(tm, 32));

    // defer-max: rescale only if some lane's tile-max exceeds m+8 (log2 units)
    if (__ballot(tm > m_q + 8.0f)) {
      const float mnew = fmaxf(m_q, tm);
      const float alpha = exp2_fast(m_q - mnew);
      m_q = mnew;
      l_q *= alpha;
      #pragma unroll
      for (int r = 0; r < 4; ++r) {
        const float ar = __shfl(alpha, 4 * g + r);   // alpha for o-row 4g+r
        #pragma unroll
        for (int n = 0; n < 4; ++n) o_acc[n][r] *= ar;
      }
    }

    // P = exp2(S - m), packed bf16, per-lane partial sum
    float ts = 0.f;
    unsigned pw[4][2];
    #pragma unroll
    for (int f = 0; f < 4; ++f) {
      float p0 = exp2_fast(st[f][0] - m_q);
      float p1 = exp2_fast(st[f][1] - m_q);
      float p2 = exp2_fast(st[f][2] - m_q);
      float p3 = exp2_fast(st[f][3] - m_q);
      ts += (p0 + p1) + (p2 + p3);
      asm("v_cvt_pk_bf16_f32 %0, %1, %2" : "=v"(pw[f][0]) : "v"(p0), "v"(p1));
      asm("v_cvt_pk_bf16_f32 %0, %1, %2" : "=v"(pw[f][1]) : "v"(p2), "v"(p3));
    }
    ts += __shfl_xor(ts, 16);
    ts += __shfl_xor(ts, 32);
    l_q += ts;

    // scatter P to Ps[q][k] (swizzled, u32 writes; addresses loop-invariant)
    {
      unsigned short* pr = &Ps[w][lq * 64];
      #pragma unroll
      for (int f = 0; f < 4; ++f) {
        *(unsigned*)&pr[(16 * f + 4 * g) ^ swzq]       = pw[f][0];
        *(unsigned*)&pr[((16 * f + 4 * g + 2) ^ swzq)] = pw[f][1];
      }
    }

    // PV: O[16 q][64 d] += P[16][64] * V[64][64]
    short8 pa0 = *(const short8*)&Ps[w][lq * 64 + (lk8 ^ swzq)];
    short8 pa1 = *(const short8*)&Ps[w][lq * 64 + ((lk8 + 32) ^ swzq)];
    __builtin_amdgcn_s_setprio(1);
    #pragma unroll
    for (int n = 0; n < 4; ++n) {
      const int rowb = (n * 16 + lq) * 64;
      short8 vb0 = *(const short8*)&Vs[cur][rowb + (lk8 ^ swzq)];
      short8 vb1 = *(const short8*)&Vs[cur][rowb + ((lk8 + 32) ^ swzq)];
      o_acc[n] = __builtin_amdgcn_mfma_f32_16x16x32_bf16(pa0, vb0, o_acc[n], 0, 0, 0);
      o_acc[n] = __builtin_amdgcn_mfma_f32_16x16x32_bf16(pa1, vb1, o_acc[n], 0, 0, 0);
    }
    __builtin_amdgcn_s_setprio(0);

    __syncthreads();   // drains prefetch into cur^1; all waves done with cur
    cur ^= 1;
  }

  // epilogue: normalize, store merged-head layout
  const int qbase = qt * 64 + w * 16 + 4 * g;
  #pragma unroll
  for (int r = 0; r < 4; ++r) {
    const float lr = __shfl(l_q, 4 * g + r);
    const float inv = 1.0f / lr;
    const int row = qbase + r;
    #pragma unroll
    for (int n = 0; n < 4; ++n)
      aout[(basebs + row) * E_ + h * HD_ + n * 16 + lq] =
          f2bf(o_acc[n][r] * inv);
  }
}

extern "C" void kernel_launch(void* const* d_in, const int* in_sizes, int n_in,
                              void* d_out, int out_size, void* d_ws, size_t ws_size,
                              hipStream_t stream) {
  const float* X  = (const float*)d_in[0];
  const float* Wa = (const float*)d_in[1];
  const float* ba = (const float*)d_in[2];
  const float* Wp = (const float*)d_in[3];
  const float* bp = (const float*)d_in[4];
  float* out = (float*)d_out;

  char* ws = (char*)d_ws;
  unsigned short* Xb  = (unsigned short*)ws; ws += (size_t)M_ * E_ * 2;    // 8 MB
  unsigned short* WaT = (unsigned short*)ws; ws += (size_t)E3_ * E_ * 2;   // 6 MB
  unsigned short* WpT = (unsigned short*)ws; ws += (size_t)E_ * E_ * 2;    // 2 MB
  unsigned short* QK  = (unsigned short*)ws; ws += (size_t)M_ * QKS * 2;   // 16 MB
  unsigned short* Vt  = (unsigned short*)ws; ws += (size_t)M_ * E_ * 2;    // 8 MB
  unsigned short* AO  = (unsigned short*)ws; ws += (size_t)M_ * E_ * 2;    // 8 MB

  cvt_f32_bf16<<<(M_ * E_ / 4 + 255) / 256, 256, 0, stream>>>(X, Xb, M_ * E_);
  transpose_bf16<<<dim3(E3_ / 32, E_ / 32), 256, 0, stream>>>(Wa, WaT, E_, E3_);
  transpose_bf16<<<dim3(E_ / 32, E_ / 32), 256, 0, stream>>>(Wp, WpT, E_, E_);
  gemm_bt_bias<1><<<dim3(E3_ / 128, M_ / 128), 256, 0, stream>>>(
      Xb, WaT, ba, nullptr, QK, Vt, M_, E3_, E_);
  flash_attn<<<dim3(B_ * H_, S_ / 64), 256, 0, stream>>>(QK, Vt, AO);
  gemm_bt_bias<0><<<dim3(E_ / 128, M_ / 128), 256, 0, stream>>>(
      AO, WpT, bp, out, nullptr, nullptr, M_, E_, E_);
}